// Round 1
// baseline (589.347 us; speedup 1.0000x reference)
//
#include <hip/hip_runtime.h>
#include <math.h>

#define NN 10000
#define FIN 512
#define HD 40
#define GEPS 1e-5f

// ---------------- degree ----------------
__global__ void k_deg(const int* __restrict__ dst, float* __restrict__ deg, int E) {
    int e = blockIdx.x * blockDim.x + threadIdx.x;
    if (e < E) atomicAdd(&deg[dst[e]], 1.0f);
}

__global__ void k_rsqrt(float* __restrict__ deg) {
    int i = blockIdx.x * blockDim.x + threadIdx.x;
    if (i < NN) deg[i] = rsqrtf(deg[i]);
}

// ---------------- h1 = x @ W1 (k-split, atomic accumulate) ----------------
#define MM1_KSPLIT 8
#define MM1_KCH 64   // 512/8
__global__ __launch_bounds__(256) void k_mm1(const float* __restrict__ x,
                                             const float* __restrict__ W1,
                                             float* __restrict__ h1) {
    __shared__ float wT[HD * MM1_KCH];   // wT[c*KCH + kk] = W1[(k0+kk)*HD + c]
    const int k0 = blockIdx.y * MM1_KCH;
    for (int idx = threadIdx.x; idx < HD * MM1_KCH; idx += 256) {
        int c = idx / MM1_KCH, kk = idx % MM1_KCH;
        wT[idx] = W1[(size_t)(k0 + kk) * HD + c];
    }
    __syncthreads();
    const int row = blockIdx.x * 256 + threadIdx.x;
    if (row >= NN) return;
    float acc[HD];
#pragma unroll
    for (int c = 0; c < HD; ++c) acc[c] = 0.0f;
    const float4* xr = (const float4*)(x + (size_t)row * FIN + k0);
#pragma unroll 2
    for (int q = 0; q < MM1_KCH / 4; ++q) {
        float4 xv = xr[q];
#pragma unroll
        for (int c = 0; c < HD; ++c) {
            float4 wv = *(const float4*)&wT[c * MM1_KCH + q * 4];
            acc[c] = fmaf(xv.x, wv.x, fmaf(xv.y, wv.y, fmaf(xv.z, wv.z, fmaf(xv.w, wv.w, acc[c]))));
        }
    }
    float* o = h1 + (size_t)row * HD;
#pragma unroll
    for (int c = 0; c < HD; ++c) atomicAdd(o + c, acc[c]);
}

// ---------------- aggregate: agg[dst] += hin[src] * coef ----------------
__global__ void k_agg(const int* __restrict__ src, const int* __restrict__ dst,
                      const float* __restrict__ dis, const float* __restrict__ hin,
                      float* __restrict__ agg, int E) {
    int t = blockIdx.x * blockDim.x + threadIdx.x;
    int e = t / (HD / 4);
    int c4 = t % (HD / 4);
    if (e >= E) return;
    int s = src[e], d = dst[e];
    float coef = dis[s] * dis[d];
    float4 v = *(const float4*)(hin + (size_t)s * HD + c4 * 4);
    float* o = agg + (size_t)d * HD + c4 * 4;
    atomicAdd(o + 0, v.x * coef);
    atomicAdd(o + 1, v.y * coef);
    atomicAdd(o + 2, v.z * coef);
    atomicAdd(o + 3, v.w * coef);
}

// ---------------- GraphNorm stats: sum and sumsq of (agg1 + b1) per column ----------------
__global__ void k_stats(const float* __restrict__ agg1, const float* __restrict__ b1,
                        float* __restrict__ stats) {
    __shared__ float s0[HD], s1[HD];
    for (int i = threadIdx.x; i < HD; i += blockDim.x) { s0[i] = 0.f; s1[i] = 0.f; }
    __syncthreads();
    const int total = NN * HD;
    for (int idx = blockIdx.x * blockDim.x + threadIdx.x; idx < total;
         idx += gridDim.x * blockDim.x) {
        int c = idx % HD;
        float v = agg1[idx] + b1[c];
        atomicAdd(&s0[c], v);
        atomicAdd(&s1[c], v * v);
    }
    __syncthreads();
    for (int i = threadIdx.x; i < HD; i += blockDim.x) {
        atomicAdd(&stats[i], s0[i]);
        atomicAdd(&stats[HD + i], s1[i]);
    }
}

// ---------------- per-column scale/shift ----------------
__global__ void k_finalize(const float* __restrict__ stats, const float* __restrict__ b1,
                           const float* __restrict__ gw, const float* __restrict__ gb,
                           const float* __restrict__ ga, float* __restrict__ colsc) {
    int c = threadIdx.x;
    if (c < HD) {
        float m   = stats[c] * (1.0f / NN);
        float ex2 = stats[HD + c] * (1.0f / NN);
        float a   = ga[c];
        float var = ex2 - 2.0f * a * m * m + a * a * m * m;
        float inv = rsqrtf(var + GEPS);
        float sc  = gw[c] * inv;
        colsc[c]      = sc;
        colsc[HD + c] = sc * (b1[c] - a * m) + gb[c];
    }
}

// ---------------- normalize + relu -> hidden ----------------
__global__ void k_norm(const float* __restrict__ agg1, const float* __restrict__ colsc,
                       float* __restrict__ hidden) {
    int idx = blockIdx.x * blockDim.x + threadIdx.x;
    if (idx < NN * HD) {
        int c = idx % HD;
        float y = fmaf(colsc[c], agg1[idx], colsc[HD + c]);
        hidden[idx] = fmaxf(y, 0.0f);
    }
}

// ---------------- heads: out = act(aggh @ W + b) ----------------
template <int ACT>
__device__ __forceinline__ float activate(float z) {
    if constexpr (ACT == 0) {          // mean: clip(exp, 1e-5, 1e6)
        return fminf(fmaxf(expf(z), 1e-5f), 1e6f);
    } else if constexpr (ACT == 1) {   // disp: clip(softplus, 1e-4, 1e4)
        float sp = fmaxf(z, 0.0f) + log1pf(expf(-fabsf(z)));
        return fminf(fmaxf(sp, 1e-4f), 1e4f);
    } else {                           // pi: sigmoid
        return 1.0f / (1.0f + expf(-z));
    }
}

template <int ACT>
__global__ __launch_bounds__(256) void k_heads(const float* __restrict__ aggh,
                                               const float* __restrict__ W,
                                               const float* __restrict__ bias,
                                               float* __restrict__ out) {
    // grid: (ceil(NN/64), 2); blockIdx.y selects column half (256 cols)
    __shared__ float wsh[HD * 256];    // 40 KB
    const int half = blockIdx.y;
    for (int idx = threadIdx.x; idx < HD * 256; idx += 256) {
        int k = idx >> 8, cc = idx & 255;
        wsh[idx] = W[(size_t)k * FIN + half * 256 + cc];
    }
    __syncthreads();
    const int wave = threadIdx.x >> 6;
    const int lane = threadIdx.x & 63;
    const int col  = lane * 4;

    for (int pass = 0; pass < 4; ++pass) {
        int rbase = blockIdx.x * 64 + pass * 16 + wave * 4;
        float4 acc[4];
#pragma unroll
        for (int r = 0; r < 4; ++r) acc[r] = make_float4(0.f, 0.f, 0.f, 0.f);
        int rr[4];
#pragma unroll
        for (int r = 0; r < 4; ++r) rr[r] = min(rbase + r, NN - 1);
#pragma unroll
        for (int k = 0; k < HD; ++k) {
            float4 wv = *(const float4*)&wsh[k * 256 + col];
#pragma unroll
            for (int r = 0; r < 4; ++r) {
                float a = aggh[(size_t)rr[r] * HD + k];
                acc[r].x = fmaf(a, wv.x, acc[r].x);
                acc[r].y = fmaf(a, wv.y, acc[r].y);
                acc[r].z = fmaf(a, wv.z, acc[r].z);
                acc[r].w = fmaf(a, wv.w, acc[r].w);
            }
        }
        int gcol = half * 256 + col;
        float4 bv = *(const float4*)&bias[gcol];
#pragma unroll
        for (int r = 0; r < 4; ++r) {
            int row = rbase + r;
            if (row < NN) {
                float4 o;
                o.x = activate<ACT>(acc[r].x + bv.x);
                o.y = activate<ACT>(acc[r].y + bv.y);
                o.z = activate<ACT>(acc[r].z + bv.z);
                o.w = activate<ACT>(acc[r].w + bv.w);
                *(float4*)&out[(size_t)row * FIN + gcol] = o;
            }
        }
    }
}

extern "C" void kernel_launch(void* const* d_in, const int* in_sizes, int n_in,
                              void* d_out, int out_size, void* d_ws, size_t ws_size,
                              hipStream_t stream) {
    const float* x   = (const float*)d_in[0];
    const int*   src = (const int*)d_in[1];
    const int*   dst = (const int*)d_in[2];
    const float* W1  = (const float*)d_in[3];
    const float* b1  = (const float*)d_in[4];
    const float* gnw = (const float*)d_in[5];
    const float* gnb = (const float*)d_in[6];
    const float* gna = (const float*)d_in[7];
    const float* Wm  = (const float*)d_in[8];
    const float* bm  = (const float*)d_in[9];
    const float* Wd  = (const float*)d_in[10];
    const float* bd  = (const float*)d_in[11];
    const float* Wp  = (const float*)d_in[12];
    const float* bp  = (const float*)d_in[13];
    const int E = in_sizes[1];

    float* ws     = (float*)d_ws;
    float* deg    = ws;                       // NN
    float* h1     = deg + NN;                 // NN*HD (atomic target)
    float* agg1   = h1 + (size_t)NN * HD;     // NN*HD (atomic target)
    float* aggh   = agg1 + (size_t)NN * HD;   // NN*HD (atomic target)
    float* stats  = aggh + (size_t)NN * HD;   // 2*HD  (atomic target)
    float* colsc  = stats + 2 * HD;           // 2*HD
    float* hidden = colsc + 2 * HD;           // NN*HD (fully written)
    float* out    = (float*)d_out;

    // zero deg + h1 + agg1 + aggh + stats + colsc in one memset
    size_t zbytes = ((size_t)NN + 3 * (size_t)NN * HD + 4 * HD) * sizeof(float);
    hipMemsetAsync(ws, 0, zbytes, stream);

    k_deg<<<(E + 255) / 256, 256, 0, stream>>>(dst, deg, E);
    k_rsqrt<<<(NN + 255) / 256, 256, 0, stream>>>(deg);
    k_mm1<<<dim3((NN + 255) / 256, MM1_KSPLIT), 256, 0, stream>>>(x, W1, h1);
    {
        int T = E * (HD / 4);
        k_agg<<<(T + 255) / 256, 256, 0, stream>>>(src, dst, deg, h1, agg1, E);
    }
    k_stats<<<256, 256, 0, stream>>>(agg1, b1, stats);
    k_finalize<<<1, 64, 0, stream>>>(stats, b1, gnw, gnb, gna, colsc);
    k_norm<<<(NN * HD + 255) / 256, 256, 0, stream>>>(agg1, colsc, hidden);
    {
        int T = E * (HD / 4);
        k_agg<<<(T + 255) / 256, 256, 0, stream>>>(src, dst, deg, hidden, aggh, E);
    }
    dim3 hgrid((NN + 63) / 64, 2);
    k_heads<0><<<hgrid, 256, 0, stream>>>(aggh, Wm, bm, out);
    k_heads<1><<<hgrid, 256, 0, stream>>>(aggh, Wd, bd, out + (size_t)NN * FIN);
    k_heads<2><<<hgrid, 256, 0, stream>>>(aggh, Wp, bp, out + 2 * (size_t)NN * FIN);
}

// Round 2
// 249.275 us; speedup vs baseline: 2.3642x; 2.3642x over previous
//
#include <hip/hip_runtime.h>
#include <math.h>

#define NN 10000
#define FIN 512
#define HD 40
#define GEPS 1e-5f

// ---------------- CSR build ----------------
__global__ void k_hist(const int* __restrict__ dst, int* __restrict__ cnt, int E) {
    int e = blockIdx.x * blockDim.x + threadIdx.x;
    if (e < E) atomicAdd(&cnt[dst[e]], 1);
}

// single block, 256 threads; chunk of 40 rows per thread (256*40 >= NN)
__global__ __launch_bounds__(256) void k_scan(const int* __restrict__ cnt,
                                              int* __restrict__ rowstart) {
    __shared__ int lds[256];
    const int t = threadIdx.x;
    const int start = t * 40;
    const int end = min(start + 40, NN);
    int s = 0;
    for (int i = start; i < end; ++i) s += cnt[i];
    lds[t] = s;
    __syncthreads();
    for (int off = 1; off < 256; off <<= 1) {
        int v = (t >= off) ? lds[t - off] : 0;
        __syncthreads();
        lds[t] += v;
        __syncthreads();
    }
    int run = lds[t] - s;   // exclusive prefix
    for (int i = start; i < end; ++i) { rowstart[i] = run; run += cnt[i]; }
    if (end == NN) rowstart[NN] = run;
}

__global__ void k_dis(const int* __restrict__ cnt, float* __restrict__ dis) {
    int i = blockIdx.x * blockDim.x + threadIdx.x;
    if (i < NN) dis[i] = rsqrtf((float)cnt[i]);
}

__global__ void k_fill(const int* __restrict__ src, const int* __restrict__ dst,
                       const int* __restrict__ rowstart, int* __restrict__ cur,
                       const float* __restrict__ dis, int2* __restrict__ csr, int E) {
    int e = blockIdx.x * blockDim.x + threadIdx.x;
    if (e >= E) return;
    int s = src[e], d = dst[e];
    int pos = rowstart[d] + atomicAdd(&cur[d], 1);
    int2 v;
    v.x = s;
    v.y = __float_as_int(dis[s] * dis[d]);
    csr[pos] = v;
}

// ---------------- h1 = x @ W1 (atomic-free, LDS cross-k reduce) ----------------
__global__ __launch_bounds__(256) void k_mm1(const float* __restrict__ x,
                                             const float* __restrict__ W1,
                                             float* __restrict__ h1) {
    __shared__ float red[256 * 41];   // 41-pad: odd stride -> conflict-free writes
    const int tid = threadIdx.x;
    const int r = tid & 63;
    const int kg = __builtin_amdgcn_readfirstlane(tid >> 6);  // wave-uniform k-group
    const int row = blockIdx.x * 64 + r;
    const int rowc = min(row, NN - 1);
    const float4* xr = (const float4*)(x + (size_t)rowc * FIN + kg * 128);
    float acc[HD];
#pragma unroll
    for (int c = 0; c < HD; ++c) acc[c] = 0.f;
#pragma unroll 4
    for (int q = 0; q < 32; ++q) {
        float4 xv = xr[q];
        const float* wbase = W1 + (size_t)(kg * 128 + q * 4) * HD;
#pragma unroll
        for (int kk = 0; kk < 4; ++kk) {
            float xs = (kk == 0) ? xv.x : (kk == 1) ? xv.y : (kk == 2) ? xv.z : xv.w;
#pragma unroll
            for (int c4 = 0; c4 < 10; ++c4) {
                float4 wv = *(const float4*)(wbase + kk * HD + c4 * 4);
                acc[c4 * 4 + 0] = fmaf(xs, wv.x, acc[c4 * 4 + 0]);
                acc[c4 * 4 + 1] = fmaf(xs, wv.y, acc[c4 * 4 + 1]);
                acc[c4 * 4 + 2] = fmaf(xs, wv.z, acc[c4 * 4 + 2]);
                acc[c4 * 4 + 3] = fmaf(xs, wv.w, acc[c4 * 4 + 3]);
            }
        }
    }
#pragma unroll
    for (int c = 0; c < HD; ++c) red[tid * 41 + c] = acc[c];
    __syncthreads();
    for (int t2 = tid; t2 < 640; t2 += 256) {
        int rr = t2 / 10, c4 = t2 % 10;
        float o0 = 0.f, o1 = 0.f, o2 = 0.f, o3 = 0.f;
#pragma unroll
        for (int kg2 = 0; kg2 < 4; ++kg2) {
            const float* p = &red[(kg2 * 64 + rr) * 41 + c4 * 4];
            o0 += p[0]; o1 += p[1]; o2 += p[2]; o3 += p[3];
        }
        int orow = blockIdx.x * 64 + rr;
        if (orow < NN)
            *(float4*)&h1[(size_t)orow * HD + c4 * 4] = make_float4(o0, o1, o2, o3);
    }
}

// ---------------- gather aggregation: agg[n] = sum_j coef*hin[csr_src[j]] ----------------
__global__ void k_gather(const int* __restrict__ rowstart, const int2* __restrict__ csr,
                         const float* __restrict__ hin, float* __restrict__ aggout) {
    int t = blockIdx.x * blockDim.x + threadIdx.x;
    if (t >= NN * 10) return;
    int n = t / 10, c4 = t % 10;
    int j0 = rowstart[n], j1 = rowstart[n + 1];
    float4 acc = make_float4(0.f, 0.f, 0.f, 0.f);
#pragma unroll 2
    for (int j = j0; j < j1; ++j) {
        int2 sc = csr[j];
        float cf = __int_as_float(sc.y);
        float4 v = *(const float4*)&hin[(size_t)sc.x * HD + c4 * 4];
        acc.x = fmaf(v.x, cf, acc.x);
        acc.y = fmaf(v.y, cf, acc.y);
        acc.z = fmaf(v.z, cf, acc.z);
        acc.w = fmaf(v.w, cf, acc.w);
    }
    *(float4*)&aggout[(size_t)n * HD + c4 * 4] = acc;
}

// ---------------- GraphNorm stats ----------------
__global__ __launch_bounds__(256) void k_stats(const float* __restrict__ agg1,
                                               const float* __restrict__ b1,
                                               float* __restrict__ stats) {
    __shared__ float s0[HD], s1[HD];
    if (threadIdx.x < HD) { s0[threadIdx.x] = 0.f; s1[threadIdx.x] = 0.f; }
    __syncthreads();
    const int gid = blockIdx.x * 256 + threadIdx.x;
    const int c4 = gid % 10;          // stride 20480 % 10 == 0 -> constant per thread
    float4 bv = ((const float4*)b1)[c4];
    float4 a0 = make_float4(0.f, 0.f, 0.f, 0.f);
    float4 a1 = a0;
    for (int i4 = gid; i4 < NN * 10; i4 += 80 * 256) {
        float4 v = ((const float4*)agg1)[i4];
        v.x += bv.x; v.y += bv.y; v.z += bv.z; v.w += bv.w;
        a0.x += v.x; a0.y += v.y; a0.z += v.z; a0.w += v.w;
        a1.x = fmaf(v.x, v.x, a1.x);
        a1.y = fmaf(v.y, v.y, a1.y);
        a1.z = fmaf(v.z, v.z, a1.z);
        a1.w = fmaf(v.w, v.w, a1.w);
    }
    atomicAdd(&s0[c4 * 4 + 0], a0.x); atomicAdd(&s0[c4 * 4 + 1], a0.y);
    atomicAdd(&s0[c4 * 4 + 2], a0.z); atomicAdd(&s0[c4 * 4 + 3], a0.w);
    atomicAdd(&s1[c4 * 4 + 0], a1.x); atomicAdd(&s1[c4 * 4 + 1], a1.y);
    atomicAdd(&s1[c4 * 4 + 2], a1.z); atomicAdd(&s1[c4 * 4 + 3], a1.w);
    __syncthreads();
    if (threadIdx.x < HD) {
        atomicAdd(&stats[threadIdx.x], s0[threadIdx.x]);
        atomicAdd(&stats[HD + threadIdx.x], s1[threadIdx.x]);
    }
}

__global__ void k_finalize(const float* __restrict__ stats, const float* __restrict__ b1,
                           const float* __restrict__ gw, const float* __restrict__ gb,
                           const float* __restrict__ ga, float* __restrict__ colsc) {
    int c = threadIdx.x;
    if (c < HD) {
        float m   = stats[c] * (1.0f / NN);
        float ex2 = stats[HD + c] * (1.0f / NN);
        float a   = ga[c];
        float var = ex2 - 2.0f * a * m * m + a * a * m * m;
        float inv = rsqrtf(var + GEPS);
        float sc  = gw[c] * inv;
        colsc[c]      = sc;
        colsc[HD + c] = sc * (b1[c] - a * m) + gb[c];
    }
}

__global__ void k_norm(const float* __restrict__ agg1, const float* __restrict__ colsc,
                       float* __restrict__ hidden) {
    int i4 = blockIdx.x * blockDim.x + threadIdx.x;
    if (i4 < NN * 10) {
        int c4 = i4 % 10;
        float4 v  = ((const float4*)agg1)[i4];
        float4 sc = ((const float4*)colsc)[c4];
        float4 sh = ((const float4*)colsc)[10 + c4];
        float4 y;
        y.x = fmaxf(fmaf(sc.x, v.x, sh.x), 0.f);
        y.y = fmaxf(fmaf(sc.y, v.y, sh.y), 0.f);
        y.z = fmaxf(fmaf(sc.z, v.z, sh.z), 0.f);
        y.w = fmaxf(fmaf(sc.w, v.w, sh.w), 0.f);
        ((float4*)hidden)[i4] = y;
    }
}

// ---------------- heads: out = act(aggh @ W + b) ----------------
template <int ACT>
__device__ __forceinline__ float activate(float z) {
    if constexpr (ACT == 0) {          // mean: clip(exp, 1e-5, 1e6)
        return fminf(fmaxf(expf(z), 1e-5f), 1e6f);
    } else if constexpr (ACT == 1) {   // disp: clip(softplus, 1e-4, 1e4)
        float sp = fmaxf(z, 0.0f) + log1pf(expf(-fabsf(z)));
        return fminf(fmaxf(sp, 1e-4f), 1e4f);
    } else {                           // pi: sigmoid
        return 1.0f / (1.0f + expf(-z));
    }
}

template <int ACT>
__global__ __launch_bounds__(256) void k_heads(const float* __restrict__ aggh,
                                               const float* __restrict__ W,
                                               const float* __restrict__ bias,
                                               float* __restrict__ out) {
    __shared__ float wsh[HD * 256];    // 40 KB
    const int half = blockIdx.y;
    for (int idx = threadIdx.x; idx < HD * 256; idx += 256) {
        int k = idx >> 8, cc = idx & 255;
        wsh[idx] = W[(size_t)k * FIN + half * 256 + cc];
    }
    __syncthreads();
    const int wave = threadIdx.x >> 6;
    const int lane = threadIdx.x & 63;
    const int col  = lane * 4;

    for (int pass = 0; pass < 4; ++pass) {
        int rbase = blockIdx.x * 64 + pass * 16 + wave * 4;
        float4 acc[4];
#pragma unroll
        for (int r = 0; r < 4; ++r) acc[r] = make_float4(0.f, 0.f, 0.f, 0.f);
        int rr[4];
#pragma unroll
        for (int r = 0; r < 4; ++r) rr[r] = min(rbase + r, NN - 1);
#pragma unroll
        for (int k = 0; k < HD; ++k) {
            float4 wv = *(const float4*)&wsh[k * 256 + col];
#pragma unroll
            for (int r = 0; r < 4; ++r) {
                float a = aggh[(size_t)rr[r] * HD + k];
                acc[r].x = fmaf(a, wv.x, acc[r].x);
                acc[r].y = fmaf(a, wv.y, acc[r].y);
                acc[r].z = fmaf(a, wv.z, acc[r].z);
                acc[r].w = fmaf(a, wv.w, acc[r].w);
            }
        }
        int gcol = half * 256 + col;
        float4 bv = *(const float4*)&bias[gcol];
#pragma unroll
        for (int r = 0; r < 4; ++r) {
            int row = rbase + r;
            if (row < NN) {
                float4 o;
                o.x = activate<ACT>(acc[r].x + bv.x);
                o.y = activate<ACT>(acc[r].y + bv.y);
                o.z = activate<ACT>(acc[r].z + bv.z);
                o.w = activate<ACT>(acc[r].w + bv.w);
                *(float4*)&out[(size_t)row * FIN + gcol] = o;
            }
        }
    }
}

extern "C" void kernel_launch(void* const* d_in, const int* in_sizes, int n_in,
                              void* d_out, int out_size, void* d_ws, size_t ws_size,
                              hipStream_t stream) {
    const float* x   = (const float*)d_in[0];
    const int*   src = (const int*)d_in[1];
    const int*   dst = (const int*)d_in[2];
    const float* W1  = (const float*)d_in[3];
    const float* b1  = (const float*)d_in[4];
    const float* gnw = (const float*)d_in[5];
    const float* gnb = (const float*)d_in[6];
    const float* gna = (const float*)d_in[7];
    const float* Wm  = (const float*)d_in[8];
    const float* bm  = (const float*)d_in[9];
    const float* Wd  = (const float*)d_in[10];
    const float* bd  = (const float*)d_in[11];
    const float* Wp  = (const float*)d_in[12];
    const float* bp  = (const float*)d_in[13];
    const int E = in_sizes[1];

    // workspace layout (16B-alignment-sensitive buffers first)
    float* ws       = (float*)d_ws;
    float* h1       = ws;                          // NN*HD (also reused as hidden)
    float* agg1     = h1 + (size_t)NN * HD;        // NN*HD (also reused as aggh)
    int2*  csr      = (int2*)(agg1 + (size_t)NN * HD);   // E int2 (8B-aligned)
    int*   cnt      = (int*)(csr + E);             // NN   } zeroed
    int*   cur      = cnt + NN;                    // NN   } zeroed
    float* stats    = (float*)(cur + NN);          // 2*HD } zeroed
    float* colsc    = stats + 2 * HD;              // 2*HD (16B-aligned: check below)
    float* dis      = colsc + 2 * HD;              // NN
    int*   rowstart = (int*)(dis + NN);            // NN+1
    float* out      = (float*)d_out;

    hipMemsetAsync(cnt, 0, (2 * (size_t)NN + 2 * HD) * sizeof(float), stream);

    k_hist<<<(E + 255) / 256, 256, 0, stream>>>(dst, cnt, E);
    k_scan<<<1, 256, 0, stream>>>(cnt, rowstart);
    k_dis<<<(NN + 255) / 256, 256, 0, stream>>>(cnt, dis);
    k_fill<<<(E + 255) / 256, 256, 0, stream>>>(src, dst, rowstart, cur, dis, csr, E);
    k_mm1<<<(NN + 63) / 64, 256, 0, stream>>>(x, W1, h1);
    k_gather<<<(NN * 10 + 255) / 256, 256, 0, stream>>>(rowstart, csr, h1, agg1);
    k_stats<<<80, 256, 0, stream>>>(agg1, b1, stats);
    k_finalize<<<1, 64, 0, stream>>>(stats, b1, gnw, gnb, gna, colsc);
    k_norm<<<(NN * 10 + 255) / 256, 256, 0, stream>>>(agg1, colsc, h1);   // hidden -> h1
    k_gather<<<(NN * 10 + 255) / 256, 256, 0, stream>>>(rowstart, csr, h1, agg1); // aggh -> agg1
    dim3 hgrid((NN + 63) / 64, 2);
    k_heads<0><<<hgrid, 256, 0, stream>>>(agg1, Wm, bm, out);
    k_heads<1><<<hgrid, 256, 0, stream>>>(agg1, Wd, bd, out + (size_t)NN * FIN);
    k_heads<2><<<hgrid, 256, 0, stream>>>(agg1, Wp, bp, out + 2 * (size_t)NN * FIN);
}

// Round 3
// 165.936 us; speedup vs baseline: 3.5516x; 1.5022x over previous
//
#include <hip/hip_runtime.h>
#include <math.h>

#define NN 10000
#define FIN 512
#define HD 40
#define GEPS 1e-5f

// ---------------- CSR build ----------------
__global__ void k_hist(const int* __restrict__ dst, int* __restrict__ cnt, int E) {
    int e = blockIdx.x * blockDim.x + threadIdx.x;
    if (e < E) atomicAdd(&cnt[dst[e]], 1);
}

// single block, 256 threads; chunk of 40 rows per thread (256*40 >= NN)
__global__ __launch_bounds__(256) void k_scan(const int* __restrict__ cnt,
                                              int* __restrict__ rowstart) {
    __shared__ int lds[256];
    const int t = threadIdx.x;
    const int start = t * 40;
    const int end = min(start + 40, NN);
    int s = 0;
    for (int i = start; i < end; ++i) s += cnt[i];
    lds[t] = s;
    __syncthreads();
    for (int off = 1; off < 256; off <<= 1) {
        int v = (t >= off) ? lds[t - off] : 0;
        __syncthreads();
        lds[t] += v;
        __syncthreads();
    }
    int run = lds[t] - s;   // exclusive prefix
    for (int i = start; i < end; ++i) { rowstart[i] = run; run += cnt[i]; }
    if (end == NN) rowstart[NN] = run;
}

__global__ void k_dis(const int* __restrict__ cnt, float* __restrict__ dis) {
    int i = blockIdx.x * blockDim.x + threadIdx.x;
    if (i < NN) dis[i] = rsqrtf((float)cnt[i]);
}

__global__ void k_fill(const int* __restrict__ src, const int* __restrict__ dst,
                       const int* __restrict__ rowstart, int* __restrict__ cur,
                       const float* __restrict__ dis, int2* __restrict__ csr, int E) {
    int e = blockIdx.x * blockDim.x + threadIdx.x;
    if (e >= E) return;
    int s = src[e], d = dst[e];
    int pos = rowstart[d] + atomicAdd(&cur[d], 1);
    int2 v;
    v.x = s;
    v.y = __float_as_int(dis[s] * dis[d]);
    csr[pos] = v;
}

// ---------------- h1 = x @ W1 (atomic-free, LDS cross-k reduce) ----------------
__global__ __launch_bounds__(256) void k_mm1(const float* __restrict__ x,
                                             const float* __restrict__ W1,
                                             float* __restrict__ h1) {
    __shared__ float red[256 * 41];   // 41-pad: odd stride -> conflict-free writes
    const int tid = threadIdx.x;
    const int r = tid & 63;
    const int kg = __builtin_amdgcn_readfirstlane(tid >> 6);  // wave-uniform k-group
    const int row = blockIdx.x * 64 + r;
    const int rowc = min(row, NN - 1);
    const float4* xr = (const float4*)(x + (size_t)rowc * FIN + kg * 128);
    float acc[HD];
#pragma unroll
    for (int c = 0; c < HD; ++c) acc[c] = 0.f;
#pragma unroll 4
    for (int q = 0; q < 32; ++q) {
        float4 xv = xr[q];
        const float* wbase = W1 + (size_t)(kg * 128 + q * 4) * HD;
#pragma unroll
        for (int kk = 0; kk < 4; ++kk) {
            float xs = (kk == 0) ? xv.x : (kk == 1) ? xv.y : (kk == 2) ? xv.z : xv.w;
#pragma unroll
            for (int c4 = 0; c4 < 10; ++c4) {
                float4 wv = *(const float4*)(wbase + kk * HD + c4 * 4);
                acc[c4 * 4 + 0] = fmaf(xs, wv.x, acc[c4 * 4 + 0]);
                acc[c4 * 4 + 1] = fmaf(xs, wv.y, acc[c4 * 4 + 1]);
                acc[c4 * 4 + 2] = fmaf(xs, wv.z, acc[c4 * 4 + 2]);
                acc[c4 * 4 + 3] = fmaf(xs, wv.w, acc[c4 * 4 + 3]);
            }
        }
    }
#pragma unroll
    for (int c = 0; c < HD; ++c) red[tid * 41 + c] = acc[c];
    __syncthreads();
    for (int t2 = tid; t2 < 640; t2 += 256) {
        int rr = t2 / 10, c4 = t2 % 10;
        float o0 = 0.f, o1 = 0.f, o2 = 0.f, o3 = 0.f;
#pragma unroll
        for (int kg2 = 0; kg2 < 4; ++kg2) {
            const float* p = &red[(kg2 * 64 + rr) * 41 + c4 * 4];
            o0 += p[0]; o1 += p[1]; o2 += p[2]; o3 += p[3];
        }
        int orow = blockIdx.x * 64 + rr;
        if (orow < NN)
            *(float4*)&h1[(size_t)orow * HD + c4 * 4] = make_float4(o0, o1, o2, o3);
    }
}

// ---------------- gather aggregation: agg[n] = sum_j coef*hin[csr_src[j]] ----------------
__global__ void k_gather(const int* __restrict__ rowstart, const int2* __restrict__ csr,
                         const float* __restrict__ hin, float* __restrict__ aggout) {
    int t = blockIdx.x * blockDim.x + threadIdx.x;
    if (t >= NN * 10) return;
    int n = t / 10, c4 = t % 10;
    int j0 = rowstart[n], j1 = rowstart[n + 1];
    float4 acc = make_float4(0.f, 0.f, 0.f, 0.f);
#pragma unroll 2
    for (int j = j0; j < j1; ++j) {
        int2 sc = csr[j];
        float cf = __int_as_float(sc.y);
        float4 v = *(const float4*)&hin[(size_t)sc.x * HD + c4 * 4];
        acc.x = fmaf(v.x, cf, acc.x);
        acc.y = fmaf(v.y, cf, acc.y);
        acc.z = fmaf(v.z, cf, acc.z);
        acc.w = fmaf(v.w, cf, acc.w);
    }
    *(float4*)&aggout[(size_t)n * HD + c4 * 4] = acc;
}

// ---------------- GraphNorm stats ----------------
__global__ __launch_bounds__(256) void k_stats(const float* __restrict__ agg1,
                                               const float* __restrict__ b1,
                                               float* __restrict__ stats) {
    __shared__ float s0[HD], s1[HD];
    if (threadIdx.x < HD) { s0[threadIdx.x] = 0.f; s1[threadIdx.x] = 0.f; }
    __syncthreads();
    const int gid = blockIdx.x * 256 + threadIdx.x;
    const int c4 = gid % 10;          // stride 20480 % 10 == 0 -> constant per thread
    float4 bv = ((const float4*)b1)[c4];
    float4 a0 = make_float4(0.f, 0.f, 0.f, 0.f);
    float4 a1 = a0;
    for (int i4 = gid; i4 < NN * 10; i4 += 80 * 256) {
        float4 v = ((const float4*)agg1)[i4];
        v.x += bv.x; v.y += bv.y; v.z += bv.z; v.w += bv.w;
        a0.x += v.x; a0.y += v.y; a0.z += v.z; a0.w += v.w;
        a1.x = fmaf(v.x, v.x, a1.x);
        a1.y = fmaf(v.y, v.y, a1.y);
        a1.z = fmaf(v.z, v.z, a1.z);
        a1.w = fmaf(v.w, v.w, a1.w);
    }
    atomicAdd(&s0[c4 * 4 + 0], a0.x); atomicAdd(&s0[c4 * 4 + 1], a0.y);
    atomicAdd(&s0[c4 * 4 + 2], a0.z); atomicAdd(&s0[c4 * 4 + 3], a0.w);
    atomicAdd(&s1[c4 * 4 + 0], a1.x); atomicAdd(&s1[c4 * 4 + 1], a1.y);
    atomicAdd(&s1[c4 * 4 + 2], a1.z); atomicAdd(&s1[c4 * 4 + 3], a1.w);
    __syncthreads();
    if (threadIdx.x < HD) {
        atomicAdd(&stats[threadIdx.x], s0[threadIdx.x]);
        atomicAdd(&stats[HD + threadIdx.x], s1[threadIdx.x]);
    }
}

__global__ void k_finalize(const float* __restrict__ stats, const float* __restrict__ b1,
                           const float* __restrict__ gw, const float* __restrict__ gb,
                           const float* __restrict__ ga, float* __restrict__ colsc) {
    int c = threadIdx.x;
    if (c < HD) {
        float m   = stats[c] * (1.0f / NN);
        float ex2 = stats[HD + c] * (1.0f / NN);
        float a   = ga[c];
        float var = ex2 - 2.0f * a * m * m + a * a * m * m;
        float inv = rsqrtf(var + GEPS);
        float sc  = gw[c] * inv;
        colsc[c]      = sc;
        colsc[HD + c] = sc * (b1[c] - a * m) + gb[c];
    }
}

__global__ void k_norm(const float* __restrict__ agg1, const float* __restrict__ colsc,
                       float* __restrict__ hidden) {
    int i4 = blockIdx.x * blockDim.x + threadIdx.x;
    if (i4 < NN * 10) {
        int c4 = i4 % 10;
        float4 v  = ((const float4*)agg1)[i4];
        float4 sc = ((const float4*)colsc)[c4];
        float4 sh = ((const float4*)colsc)[10 + c4];
        float4 y;
        y.x = fmaxf(fmaf(sc.x, v.x, sh.x), 0.f);
        y.y = fmaxf(fmaf(sc.y, v.y, sh.y), 0.f);
        y.z = fmaxf(fmaf(sc.z, v.z, sh.z), 0.f);
        y.w = fmaxf(fmaf(sc.w, v.w, sh.w), 0.f);
        ((float4*)hidden)[i4] = y;
    }
}

// ---------------- heads: out = act(aggh @ W + b) ----------------
template <int ACT>
__device__ __forceinline__ float activate(float z) {
    if constexpr (ACT == 0) {          // mean: clip(exp, 1e-5, 1e6)
        return fminf(fmaxf(__expf(z), 1e-5f), 1e6f);
    } else if constexpr (ACT == 1) {   // disp: clip(softplus, 1e-4, 1e4)
        float sp = fmaxf(z, 0.0f) + __logf(1.0f + __expf(-fabsf(z)));
        return fminf(fmaxf(sp, 1e-4f), 1e4f);
    } else {                           // pi: sigmoid
        return __fdividef(1.0f, 1.0f + __expf(-z));
    }
}

// grid (ceil(NN/128), 4). Block: 128 rows x 128 cols. Thread: 16 rows x 4 cols.
template <int ACT>
__global__ __launch_bounds__(256, 4) void k_heads(const float* __restrict__ aggh,
                                                  const float* __restrict__ W,
                                                  const float* __restrict__ bias,
                                                  float* __restrict__ out) {
    __shared__ float4 w_s[40 * 32];   // [k][32 float4-cols], 20 KB
    __shared__ float4 a_s[40 * 32];   // k-major, rotated 4-slot subtiles, 20 KB
    const int t = threadIdx.x;
    const int rowbase = blockIdx.x * 128;
    const int colbase = blockIdx.y * 128;

    // stage W chunk [40][128] (straight copy, coalesced, conflict-free)
    const float4* W4 = (const float4*)W;
#pragma unroll
    for (int q = 0; q < 5; ++q) {
        int idx4 = t + 256 * q;
        int k = idx4 >> 5, cw = idx4 & 31;
        w_s[idx4] = W4[(size_t)k * 128 + (colbase >> 2) + cw];
    }
    // stage aggh tile transposed to k-major with c4-rotation (<=3-way wr conflicts)
    const float4* A4 = (const float4*)aggh;
    float* as = (float*)a_s;
#pragma unroll
    for (int q = 0; q < 5; ++q) {
        int idx4 = t + 256 * q;                 // 1280 float4s = 128 rows x 10
        int row = idx4 / 10, c4 = idx4 % 10;
        int grow = min(rowbase + row, NN - 1);
        float4 v = A4[(size_t)grow * 10 + c4];
        int p = (row & ~15) + (((row & 15) + ((c4 & 3) << 2)) & 15);
        int k0 = c4 << 2;
        as[(k0 + 0) * 128 + p] = v.x;
        as[(k0 + 1) * 128 + p] = v.y;
        as[(k0 + 2) * 128 + p] = v.z;
        as[(k0 + 3) * 128 + p] = v.w;
    }
    __syncthreads();

    const int cg = t & 31;        // float4 column within block
    const int rg = t >> 5;        // 16-row group (0..7)

    float4 acc[16];
#pragma unroll
    for (int r = 0; r < 16; ++r) acc[r] = make_float4(0.f, 0.f, 0.f, 0.f);

#pragma unroll 2
    for (int kc = 0; kc < 10; ++kc) {
        const int rot = kc & 3;
#pragma unroll
        for (int kk = 0; kk < 4; ++kk) {
            const int k = (kc << 2) + kk;
            float4 wv = w_s[(k << 5) + cg];
#pragma unroll
            for (int jb = 0; jb < 4; ++jb) {
                float4 av = a_s[(k << 5) + (rg << 2) + ((jb + rot) & 3)];
                const int r0 = jb << 2;
                acc[r0 + 0].x = fmaf(av.x, wv.x, acc[r0 + 0].x);
                acc[r0 + 0].y = fmaf(av.x, wv.y, acc[r0 + 0].y);
                acc[r0 + 0].z = fmaf(av.x, wv.z, acc[r0 + 0].z);
                acc[r0 + 0].w = fmaf(av.x, wv.w, acc[r0 + 0].w);
                acc[r0 + 1].x = fmaf(av.y, wv.x, acc[r0 + 1].x);
                acc[r0 + 1].y = fmaf(av.y, wv.y, acc[r0 + 1].y);
                acc[r0 + 1].z = fmaf(av.y, wv.z, acc[r0 + 1].z);
                acc[r0 + 1].w = fmaf(av.y, wv.w, acc[r0 + 1].w);
                acc[r0 + 2].x = fmaf(av.z, wv.x, acc[r0 + 2].x);
                acc[r0 + 2].y = fmaf(av.z, wv.y, acc[r0 + 2].y);
                acc[r0 + 2].z = fmaf(av.z, wv.z, acc[r0 + 2].z);
                acc[r0 + 2].w = fmaf(av.z, wv.w, acc[r0 + 2].w);
                acc[r0 + 3].x = fmaf(av.w, wv.x, acc[r0 + 3].x);
                acc[r0 + 3].y = fmaf(av.w, wv.y, acc[r0 + 3].y);
                acc[r0 + 3].z = fmaf(av.w, wv.z, acc[r0 + 3].z);
                acc[r0 + 3].w = fmaf(av.w, wv.w, acc[r0 + 3].w);
            }
        }
    }

    const int col = colbase + (cg << 2);
    float4 bv = *(const float4*)&bias[col];
    float4* out4 = (float4*)out;
#pragma unroll
    for (int r = 0; r < 16; ++r) {
        int grow = rowbase + (rg << 4) + r;
        if (grow < NN) {
            float4 o;
            o.x = activate<ACT>(acc[r].x + bv.x);
            o.y = activate<ACT>(acc[r].y + bv.y);
            o.z = activate<ACT>(acc[r].z + bv.z);
            o.w = activate<ACT>(acc[r].w + bv.w);
            out4[(size_t)grow * 128 + (col >> 2)] = o;
        }
    }
}

extern "C" void kernel_launch(void* const* d_in, const int* in_sizes, int n_in,
                              void* d_out, int out_size, void* d_ws, size_t ws_size,
                              hipStream_t stream) {
    const float* x   = (const float*)d_in[0];
    const int*   src = (const int*)d_in[1];
    const int*   dst = (const int*)d_in[2];
    const float* W1  = (const float*)d_in[3];
    const float* b1  = (const float*)d_in[4];
    const float* gnw = (const float*)d_in[5];
    const float* gnb = (const float*)d_in[6];
    const float* gna = (const float*)d_in[7];
    const float* Wm  = (const float*)d_in[8];
    const float* bm  = (const float*)d_in[9];
    const float* Wd  = (const float*)d_in[10];
    const float* bd  = (const float*)d_in[11];
    const float* Wp  = (const float*)d_in[12];
    const float* bp  = (const float*)d_in[13];
    const int E = in_sizes[1];

    // workspace layout (16B-alignment-sensitive buffers first)
    float* ws       = (float*)d_ws;
    float* h1       = ws;                          // NN*HD (also reused as hidden)
    float* agg1     = h1 + (size_t)NN * HD;        // NN*HD (also reused as aggh)
    int2*  csr      = (int2*)(agg1 + (size_t)NN * HD);   // E int2 (8B-aligned)
    int*   cnt      = (int*)(csr + E);             // NN   } zeroed
    int*   cur      = cnt + NN;                    // NN   } zeroed
    float* stats    = (float*)(cur + NN);          // 2*HD } zeroed
    float* colsc    = stats + 2 * HD;              // 2*HD
    float* dis      = colsc + 2 * HD;              // NN
    int*   rowstart = (int*)(dis + NN);            // NN+1
    float* out      = (float*)d_out;

    hipMemsetAsync(cnt, 0, (2 * (size_t)NN + 2 * HD) * sizeof(float), stream);

    k_hist<<<(E + 255) / 256, 256, 0, stream>>>(dst, cnt, E);
    k_scan<<<1, 256, 0, stream>>>(cnt, rowstart);
    k_dis<<<(NN + 255) / 256, 256, 0, stream>>>(cnt, dis);
    k_fill<<<(E + 255) / 256, 256, 0, stream>>>(src, dst, rowstart, cur, dis, csr, E);
    k_mm1<<<(NN + 63) / 64, 256, 0, stream>>>(x, W1, h1);
    k_gather<<<(NN * 10 + 255) / 256, 256, 0, stream>>>(rowstart, csr, h1, agg1);
    k_stats<<<80, 256, 0, stream>>>(agg1, b1, stats);
    k_finalize<<<1, 64, 0, stream>>>(stats, b1, gnw, gnb, gna, colsc);
    k_norm<<<(NN * 10 + 255) / 256, 256, 0, stream>>>(agg1, colsc, h1);   // hidden -> h1
    k_gather<<<(NN * 10 + 255) / 256, 256, 0, stream>>>(rowstart, csr, h1, agg1); // aggh -> agg1
    dim3 hgrid((NN + 127) / 128, 4);
    k_heads<0><<<hgrid, 256, 0, stream>>>(agg1, Wm, bm, out);
    k_heads<1><<<hgrid, 256, 0, stream>>>(agg1, Wd, bd, out + (size_t)NN * FIN);
    k_heads<2><<<hgrid, 256, 0, stream>>>(agg1, Wp, bp, out + 2 * (size_t)NN * FIN);
}

// Round 4
// 151.370 us; speedup vs baseline: 3.8934x; 1.0962x over previous
//
#include <hip/hip_runtime.h>
#include <math.h>

#define NN 10000
#define FIN 512
#define HD 40
#define GEPS 1e-5f

// ---------------- zero cnt/cur/stats (replaces pathological rocclr fill) ----------------
#define ZI4 ((2 * NN + 2 * HD) / 4)   // 5020 int4s
__global__ void k_zero(int4* __restrict__ p) {
    int i = blockIdx.x * blockDim.x + threadIdx.x;
    if (i < ZI4) p[i] = make_int4(0, 0, 0, 0);
}

// ---------------- CSR build ----------------
__global__ void k_hist(const int* __restrict__ dst, int* __restrict__ cnt, int E) {
    int e = blockIdx.x * blockDim.x + threadIdx.x;
    if (e < E) atomicAdd(&cnt[dst[e]], 1);
}

// single block, 256 threads; chunk of 40 rows per thread (256*40 >= NN); fused dis=rsqrt(deg)
__global__ __launch_bounds__(256) void k_scan(const int* __restrict__ cnt,
                                              int* __restrict__ rowstart,
                                              float* __restrict__ dis) {
    __shared__ int lds[256];
    const int t = threadIdx.x;
    const int start = t * 40;
    const int end = min(start + 40, NN);
    int s = 0;
    for (int i = start; i < end; ++i) s += cnt[i];
    lds[t] = s;
    __syncthreads();
    for (int off = 1; off < 256; off <<= 1) {
        int v = (t >= off) ? lds[t - off] : 0;
        __syncthreads();
        lds[t] += v;
        __syncthreads();
    }
    int run = lds[t] - s;   // exclusive prefix
    for (int i = start; i < end; ++i) {
        int c = cnt[i];
        rowstart[i] = run;
        run += c;
        dis[i] = rsqrtf((float)c);
    }
    if (end == NN) rowstart[NN] = run;
}

__global__ void k_fill(const int* __restrict__ src, const int* __restrict__ dst,
                       const int* __restrict__ rowstart, int* __restrict__ cur,
                       const float* __restrict__ dis, int2* __restrict__ csr, int E) {
    int e = blockIdx.x * blockDim.x + threadIdx.x;
    if (e >= E) return;
    int s = src[e], d = dst[e];
    int pos = rowstart[d] + atomicAdd(&cur[d], 1);
    int2 v;
    v.x = s;
    v.y = __float_as_int(dis[s] * dis[d]);
    csr[pos] = v;
}

// ---------------- h1 = x @ W1 (atomic-free, LDS cross-k reduce) ----------------
__global__ __launch_bounds__(256) void k_mm1(const float* __restrict__ x,
                                             const float* __restrict__ W1,
                                             float* __restrict__ h1) {
    __shared__ float red[256 * 41];   // 41-pad: odd stride -> conflict-free writes
    const int tid = threadIdx.x;
    const int r = tid & 63;
    const int kg = __builtin_amdgcn_readfirstlane(tid >> 6);  // wave-uniform k-group
    const int row = blockIdx.x * 64 + r;
    const int rowc = min(row, NN - 1);
    const float4* xr = (const float4*)(x + (size_t)rowc * FIN + kg * 128);
    float acc[HD];
#pragma unroll
    for (int c = 0; c < HD; ++c) acc[c] = 0.f;
#pragma unroll 4
    for (int q = 0; q < 32; ++q) {
        float4 xv = xr[q];
        const float* wbase = W1 + (size_t)(kg * 128 + q * 4) * HD;
#pragma unroll
        for (int kk = 0; kk < 4; ++kk) {
            float xs = (kk == 0) ? xv.x : (kk == 1) ? xv.y : (kk == 2) ? xv.z : xv.w;
#pragma unroll
            for (int c4 = 0; c4 < 10; ++c4) {
                float4 wv = *(const float4*)(wbase + kk * HD + c4 * 4);
                acc[c4 * 4 + 0] = fmaf(xs, wv.x, acc[c4 * 4 + 0]);
                acc[c4 * 4 + 1] = fmaf(xs, wv.y, acc[c4 * 4 + 1]);
                acc[c4 * 4 + 2] = fmaf(xs, wv.z, acc[c4 * 4 + 2]);
                acc[c4 * 4 + 3] = fmaf(xs, wv.w, acc[c4 * 4 + 3]);
            }
        }
    }
#pragma unroll
    for (int c = 0; c < HD; ++c) red[tid * 41 + c] = acc[c];
    __syncthreads();
    for (int t2 = tid; t2 < 640; t2 += 256) {
        int rr = t2 / 10, c4 = t2 % 10;
        float o0 = 0.f, o1 = 0.f, o2 = 0.f, o3 = 0.f;
#pragma unroll
        for (int kg2 = 0; kg2 < 4; ++kg2) {
            const float* p = &red[(kg2 * 64 + rr) * 41 + c4 * 4];
            o0 += p[0]; o1 += p[1]; o2 += p[2]; o3 += p[3];
        }
        int orow = blockIdx.x * 64 + rr;
        if (orow < NN)
            *(float4*)&h1[(size_t)orow * HD + c4 * 4] = make_float4(o0, o1, o2, o3);
    }
}

// ---------------- gather aggregation: agg[n] = sum_j coef * f(hin[csr_src[j]]) ----------------
// NORM: f(v) = relu(sc*v + sh) applied on the fly (fuses the k_norm pass)
template <bool NORM>
__global__ void k_gather(const int* __restrict__ rowstart, const int2* __restrict__ csr,
                         const float* __restrict__ hin, const float* __restrict__ colsc,
                         float* __restrict__ aggout) {
    int t = blockIdx.x * blockDim.x + threadIdx.x;
    if (t >= NN * 10) return;
    int n = t / 10, c4 = t % 10;
    int j0 = rowstart[n], j1 = rowstart[n + 1];
    float4 sc, sh;
    if (NORM) {
        sc = ((const float4*)colsc)[c4];
        sh = ((const float4*)colsc)[10 + c4];
    }
    float4 acc = make_float4(0.f, 0.f, 0.f, 0.f);
#pragma unroll 2
    for (int j = j0; j < j1; ++j) {
        int2 se = csr[j];
        float cf = __int_as_float(se.y);
        float4 v = *(const float4*)&hin[(size_t)se.x * HD + c4 * 4];
        if (NORM) {
            v.x = fmaxf(fmaf(sc.x, v.x, sh.x), 0.f);
            v.y = fmaxf(fmaf(sc.y, v.y, sh.y), 0.f);
            v.z = fmaxf(fmaf(sc.z, v.z, sh.z), 0.f);
            v.w = fmaxf(fmaf(sc.w, v.w, sh.w), 0.f);
        }
        acc.x = fmaf(v.x, cf, acc.x);
        acc.y = fmaf(v.y, cf, acc.y);
        acc.z = fmaf(v.z, cf, acc.z);
        acc.w = fmaf(v.w, cf, acc.w);
    }
    *(float4*)&aggout[(size_t)n * HD + c4 * 4] = acc;
}

// ---------------- GraphNorm stats ----------------
__global__ __launch_bounds__(256) void k_stats(const float* __restrict__ agg1,
                                               const float* __restrict__ b1,
                                               float* __restrict__ stats) {
    __shared__ float s0[HD], s1[HD];
    if (threadIdx.x < HD) { s0[threadIdx.x] = 0.f; s1[threadIdx.x] = 0.f; }
    __syncthreads();
    const int gid = blockIdx.x * 256 + threadIdx.x;
    const int c4 = gid % 10;          // stride 20480 % 10 == 0 -> constant per thread
    float4 bv = ((const float4*)b1)[c4];
    float4 a0 = make_float4(0.f, 0.f, 0.f, 0.f);
    float4 a1 = a0;
    for (int i4 = gid; i4 < NN * 10; i4 += 80 * 256) {
        float4 v = ((const float4*)agg1)[i4];
        v.x += bv.x; v.y += bv.y; v.z += bv.z; v.w += bv.w;
        a0.x += v.x; a0.y += v.y; a0.z += v.z; a0.w += v.w;
        a1.x = fmaf(v.x, v.x, a1.x);
        a1.y = fmaf(v.y, v.y, a1.y);
        a1.z = fmaf(v.z, v.z, a1.z);
        a1.w = fmaf(v.w, v.w, a1.w);
    }
    atomicAdd(&s0[c4 * 4 + 0], a0.x); atomicAdd(&s0[c4 * 4 + 1], a0.y);
    atomicAdd(&s0[c4 * 4 + 2], a0.z); atomicAdd(&s0[c4 * 4 + 3], a0.w);
    atomicAdd(&s1[c4 * 4 + 0], a1.x); atomicAdd(&s1[c4 * 4 + 1], a1.y);
    atomicAdd(&s1[c4 * 4 + 2], a1.z); atomicAdd(&s1[c4 * 4 + 3], a1.w);
    __syncthreads();
    if (threadIdx.x < HD) {
        atomicAdd(&stats[threadIdx.x], s0[threadIdx.x]);
        atomicAdd(&stats[HD + threadIdx.x], s1[threadIdx.x]);
    }
}

__global__ void k_finalize(const float* __restrict__ stats, const float* __restrict__ b1,
                           const float* __restrict__ gw, const float* __restrict__ gb,
                           const float* __restrict__ ga, float* __restrict__ colsc) {
    int c = threadIdx.x;
    if (c < HD) {
        float m   = stats[c] * (1.0f / NN);
        float ex2 = stats[HD + c] * (1.0f / NN);
        float a   = ga[c];
        float var = ex2 - 2.0f * a * m * m + a * a * m * m;
        float inv = rsqrtf(var + GEPS);
        float sc  = gw[c] * inv;
        colsc[c]      = sc;
        colsc[HD + c] = sc * (b1[c] - a * m) + gb[c];
    }
}

// ---------------- heads (all three in one dispatch; z selects head) ----------------
__device__ __forceinline__ float activate_rt(float z, int act) {
    if (act == 0) {                    // mean: clip(exp, 1e-5, 1e6)
        return fminf(fmaxf(__expf(z), 1e-5f), 1e6f);
    } else if (act == 1) {             // disp: clip(softplus, 1e-4, 1e4)
        float sp = fmaxf(z, 0.0f) + __logf(1.0f + __expf(-fabsf(z)));
        return fminf(fmaxf(sp, 1e-4f), 1e4f);
    }
    return __fdividef(1.0f, 1.0f + __expf(-z));   // pi: sigmoid
}

// grid (ceil(NN/128), 4, 3). Block: 128 rows x 128 cols. Thread: 16 rows x 4 cols.
__global__ __launch_bounds__(256, 4) void k_heads3(const float* __restrict__ aggh,
                                                   const float* __restrict__ Wm,
                                                   const float* __restrict__ bm,
                                                   const float* __restrict__ Wd,
                                                   const float* __restrict__ bd,
                                                   const float* __restrict__ Wp,
                                                   const float* __restrict__ bp,
                                                   float* __restrict__ out) {
    __shared__ float4 w_s[40 * 32];   // [k][32 float4-cols], 20 KB
    __shared__ float4 a_s[40 * 32];   // k-major, rotated 4-slot subtiles, 20 KB
    const int z = blockIdx.z;
    const float* W    = (z == 0) ? Wm : (z == 1) ? Wd : Wp;
    const float* bias = (z == 0) ? bm : (z == 1) ? bd : bp;
    float* o = out + (size_t)z * NN * FIN;

    const int t = threadIdx.x;
    const int rowbase = blockIdx.x * 128;
    const int colbase = blockIdx.y * 128;

    // stage W chunk [40][128] (straight copy, coalesced, conflict-free)
    const float4* W4 = (const float4*)W;
#pragma unroll
    for (int q = 0; q < 5; ++q) {
        int idx4 = t + 256 * q;
        int k = idx4 >> 5, cw = idx4 & 31;
        w_s[idx4] = W4[(size_t)k * 128 + (colbase >> 2) + cw];
    }
    // stage aggh tile transposed to k-major with c4-rotation (<=3-way wr conflicts)
    const float4* A4 = (const float4*)aggh;
    float* as = (float*)a_s;
#pragma unroll
    for (int q = 0; q < 5; ++q) {
        int idx4 = t + 256 * q;                 // 1280 float4s = 128 rows x 10
        int row = idx4 / 10, c4 = idx4 % 10;
        int grow = min(rowbase + row, NN - 1);
        float4 v = A4[(size_t)grow * 10 + c4];
        int p = (row & ~15) + (((row & 15) + ((c4 & 3) << 2)) & 15);
        int k0 = c4 << 2;
        as[(k0 + 0) * 128 + p] = v.x;
        as[(k0 + 1) * 128 + p] = v.y;
        as[(k0 + 2) * 128 + p] = v.z;
        as[(k0 + 3) * 128 + p] = v.w;
    }
    __syncthreads();

    const int cg = t & 31;        // float4 column within block
    const int rg = t >> 5;        // 16-row group (0..7)

    float4 acc[16];
#pragma unroll
    for (int r = 0; r < 16; ++r) acc[r] = make_float4(0.f, 0.f, 0.f, 0.f);

#pragma unroll 2
    for (int kc = 0; kc < 10; ++kc) {
        const int rot = kc & 3;
#pragma unroll
        for (int kk = 0; kk < 4; ++kk) {
            const int k = (kc << 2) + kk;
            float4 wv = w_s[(k << 5) + cg];
#pragma unroll
            for (int jb = 0; jb < 4; ++jb) {
                float4 av = a_s[(k << 5) + (rg << 2) + ((jb + rot) & 3)];
                const int r0 = jb << 2;
                acc[r0 + 0].x = fmaf(av.x, wv.x, acc[r0 + 0].x);
                acc[r0 + 0].y = fmaf(av.x, wv.y, acc[r0 + 0].y);
                acc[r0 + 0].z = fmaf(av.x, wv.z, acc[r0 + 0].z);
                acc[r0 + 0].w = fmaf(av.x, wv.w, acc[r0 + 0].w);
                acc[r0 + 1].x = fmaf(av.y, wv.x, acc[r0 + 1].x);
                acc[r0 + 1].y = fmaf(av.y, wv.y, acc[r0 + 1].y);
                acc[r0 + 1].z = fmaf(av.y, wv.z, acc[r0 + 1].z);
                acc[r0 + 1].w = fmaf(av.y, wv.w, acc[r0 + 1].w);
                acc[r0 + 2].x = fmaf(av.z, wv.x, acc[r0 + 2].x);
                acc[r0 + 2].y = fmaf(av.z, wv.y, acc[r0 + 2].y);
                acc[r0 + 2].z = fmaf(av.z, wv.z, acc[r0 + 2].z);
                acc[r0 + 2].w = fmaf(av.z, wv.w, acc[r0 + 2].w);
                acc[r0 + 3].x = fmaf(av.w, wv.x, acc[r0 + 3].x);
                acc[r0 + 3].y = fmaf(av.w, wv.y, acc[r0 + 3].y);
                acc[r0 + 3].z = fmaf(av.w, wv.z, acc[r0 + 3].z);
                acc[r0 + 3].w = fmaf(av.w, wv.w, acc[r0 + 3].w);
            }
        }
    }

    const int col = colbase + (cg << 2);
    float4 bv = *(const float4*)&bias[col];
    float4* out4 = (float4*)o;
#pragma unroll
    for (int r = 0; r < 16; ++r) {
        int grow = rowbase + (rg << 4) + r;
        if (grow < NN) {
            float4 ov;
            ov.x = activate_rt(acc[r].x + bv.x, z);
            ov.y = activate_rt(acc[r].y + bv.y, z);
            ov.z = activate_rt(acc[r].z + bv.z, z);
            ov.w = activate_rt(acc[r].w + bv.w, z);
            out4[(size_t)grow * 128 + (col >> 2)] = ov;
        }
    }
}

extern "C" void kernel_launch(void* const* d_in, const int* in_sizes, int n_in,
                              void* d_out, int out_size, void* d_ws, size_t ws_size,
                              hipStream_t stream) {
    const float* x   = (const float*)d_in[0];
    const int*   src = (const int*)d_in[1];
    const int*   dst = (const int*)d_in[2];
    const float* W1  = (const float*)d_in[3];
    const float* b1  = (const float*)d_in[4];
    const float* gnw = (const float*)d_in[5];
    const float* gnb = (const float*)d_in[6];
    const float* gna = (const float*)d_in[7];
    const float* Wm  = (const float*)d_in[8];
    const float* bm  = (const float*)d_in[9];
    const float* Wd  = (const float*)d_in[10];
    const float* bd  = (const float*)d_in[11];
    const float* Wp  = (const float*)d_in[12];
    const float* bp  = (const float*)d_in[13];
    const int E = in_sizes[1];

    // workspace layout: zero-region (cnt,cur,stats) is 16B-aligned by construction
    float* ws       = (float*)d_ws;
    float* h1       = ws;                          // NN*HD  (mm1 out; later aggh)
    float* agg1     = h1 + (size_t)NN * HD;        // NN*HD  (gather1 out)
    int*   cnt      = (int*)(agg1 + (size_t)NN * HD);  // NN   } zeroed (int4)
    int*   cur      = cnt + NN;                    // NN     } zeroed
    float* stats    = (float*)(cur + NN);          // 2*HD   } zeroed
    float* colsc    = stats + 2 * HD;              // 2*HD
    float* dis      = colsc + 2 * HD;              // NN
    int*   rowstart = (int*)(dis + NN);            // NN+1 (+1 pad for int2 align)
    int2*  csr      = (int2*)(rowstart + NN + 2);  // E int2, 8B-aligned
    float* out      = (float*)d_out;

    k_zero<<<(ZI4 + 255) / 256, 256, 0, stream>>>((int4*)cnt);
    k_hist<<<(E + 255) / 256, 256, 0, stream>>>(dst, cnt, E);
    k_scan<<<1, 256, 0, stream>>>(cnt, rowstart, dis);
    k_fill<<<(E + 255) / 256, 256, 0, stream>>>(src, dst, rowstart, cur, dis, csr, E);
    k_mm1<<<(NN + 63) / 64, 256, 0, stream>>>(x, W1, h1);
    k_gather<false><<<(NN * 10 + 255) / 256, 256, 0, stream>>>(rowstart, csr, h1, nullptr, agg1);
    k_stats<<<80, 256, 0, stream>>>(agg1, b1, stats);
    k_finalize<<<1, 64, 0, stream>>>(stats, b1, gnw, gnb, gna, colsc);
    // fused norm+relu+aggregate: reads agg1, writes aggh into h1
    k_gather<true><<<(NN * 10 + 255) / 256, 256, 0, stream>>>(rowstart, csr, agg1, colsc, h1);
    dim3 hgrid((NN + 127) / 128, 4, 3);
    k_heads3<<<hgrid, 256, 0, stream>>>(h1, Wm, bm, Wd, bd, Wp, bp, out);
}

// Round 5
// 147.731 us; speedup vs baseline: 3.9893x; 1.0246x over previous
//
#include <hip/hip_runtime.h>
#include <math.h>

#define NN 10000
#define FIN 512
#define HD 40
#define GEPS 1e-5f

// ---------------- zero cnt/cur/stats ----------------
#define ZI4 ((2 * NN + 2 * HD) / 4)   // 5020 int4s
__global__ void k_zero(int4* __restrict__ p) {
    int i = blockIdx.x * blockDim.x + threadIdx.x;
    if (i < ZI4) p[i] = make_int4(0, 0, 0, 0);
}

// ---------------- CSR build ----------------
__global__ void k_hist(const int* __restrict__ dst, int* __restrict__ cnt, int E) {
    int e = blockIdx.x * blockDim.x + threadIdx.x;
    if (e < E) atomicAdd(&cnt[dst[e]], 1);
}

// single block, 256 threads; fused dis=rsqrt(deg)
__global__ __launch_bounds__(256) void k_scan(const int* __restrict__ cnt,
                                              int* __restrict__ rowstart,
                                              float* __restrict__ dis) {
    __shared__ int lds[256];
    const int t = threadIdx.x;
    const int start = t * 40;
    const int end = min(start + 40, NN);
    int s = 0;
    for (int i = start; i < end; ++i) s += cnt[i];
    lds[t] = s;
    __syncthreads();
    for (int off = 1; off < 256; off <<= 1) {
        int v = (t >= off) ? lds[t - off] : 0;
        __syncthreads();
        lds[t] += v;
        __syncthreads();
    }
    int run = lds[t] - s;   // exclusive prefix
    for (int i = start; i < end; ++i) {
        int c = cnt[i];
        rowstart[i] = run;
        run += c;
        dis[i] = rsqrtf((float)c);
    }
    if (end == NN) rowstart[NN] = run;
}

__global__ void k_fill(const int* __restrict__ src, const int* __restrict__ dst,
                       const int* __restrict__ rowstart, int* __restrict__ cur,
                       const float* __restrict__ dis, int2* __restrict__ csr, int E) {
    int e = blockIdx.x * blockDim.x + threadIdx.x;
    if (e >= E) return;
    int s = src[e], d = dst[e];
    int pos = rowstart[d] + atomicAdd(&cur[d], 1);
    int2 v;
    v.x = s;
    v.y = __float_as_int(dis[s] * dis[d]);
    csr[pos] = v;
}

// ---------------- h1 = x @ W1 (atomic-free, LDS cross-k reduce) ----------------
__global__ __launch_bounds__(256) void k_mm1(const float* __restrict__ x,
                                             const float* __restrict__ W1,
                                             float* __restrict__ h1) {
    __shared__ float red[256 * 41];   // 41-pad: odd stride -> conflict-free writes
    const int tid = threadIdx.x;
    const int r = tid & 63;
    const int kg = __builtin_amdgcn_readfirstlane(tid >> 6);  // wave-uniform k-group
    const int row = blockIdx.x * 64 + r;
    const int rowc = min(row, NN - 1);
    const float4* xr = (const float4*)(x + (size_t)rowc * FIN + kg * 128);
    float acc[HD];
#pragma unroll
    for (int c = 0; c < HD; ++c) acc[c] = 0.f;
#pragma unroll 4
    for (int q = 0; q < 32; ++q) {
        float4 xv = xr[q];
        const float* wbase = W1 + (size_t)(kg * 128 + q * 4) * HD;
#pragma unroll
        for (int kk = 0; kk < 4; ++kk) {
            float xs = (kk == 0) ? xv.x : (kk == 1) ? xv.y : (kk == 2) ? xv.z : xv.w;
#pragma unroll
            for (int c4 = 0; c4 < 10; ++c4) {
                float4 wv = *(const float4*)(wbase + kk * HD + c4 * 4);
                acc[c4 * 4 + 0] = fmaf(xs, wv.x, acc[c4 * 4 + 0]);
                acc[c4 * 4 + 1] = fmaf(xs, wv.y, acc[c4 * 4 + 1]);
                acc[c4 * 4 + 2] = fmaf(xs, wv.z, acc[c4 * 4 + 2]);
                acc[c4 * 4 + 3] = fmaf(xs, wv.w, acc[c4 * 4 + 3]);
            }
        }
    }
#pragma unroll
    for (int c = 0; c < HD; ++c) red[tid * 41 + c] = acc[c];
    __syncthreads();
    for (int t2 = tid; t2 < 640; t2 += 256) {
        int rr = t2 / 10, c4 = t2 % 10;
        float o0 = 0.f, o1 = 0.f, o2 = 0.f, o3 = 0.f;
#pragma unroll
        for (int kg2 = 0; kg2 < 4; ++kg2) {
            const float* p = &red[(kg2 * 64 + rr) * 41 + c4 * 4];
            o0 += p[0]; o1 += p[1]; o2 += p[2]; o3 += p[3];
        }
        int orow = blockIdx.x * 64 + rr;
        if (orow < NN)
            *(float4*)&h1[(size_t)orow * HD + c4 * 4] = make_float4(o0, o1, o2, o3);
    }
}

// ---------------- gather1: agg1[n] = sum coef*h1[src] ; fused GraphNorm stats ----------------
__global__ __launch_bounds__(256) void k_gather1(const int* __restrict__ rowstart,
                                                 const int2* __restrict__ csr,
                                                 const float* __restrict__ hin,
                                                 const float* __restrict__ b1,
                                                 float* __restrict__ agg1,
                                                 float* __restrict__ stats) {
    __shared__ float s0[HD], s1[HD];
    if (threadIdx.x < HD) { s0[threadIdx.x] = 0.f; s1[threadIdx.x] = 0.f; }
    __syncthreads();
    int t = blockIdx.x * 256 + threadIdx.x;
    if (t < NN * 10) {
        int n = t / 10, c4 = t % 10;
        int j0 = rowstart[n], j1 = rowstart[n + 1];
        float4 acc = make_float4(0.f, 0.f, 0.f, 0.f);
#pragma unroll 2
        for (int j = j0; j < j1; ++j) {
            int2 se = csr[j];
            float cf = __int_as_float(se.y);
            float4 v = *(const float4*)&hin[(size_t)se.x * HD + c4 * 4];
            acc.x = fmaf(v.x, cf, acc.x);
            acc.y = fmaf(v.y, cf, acc.y);
            acc.z = fmaf(v.z, cf, acc.z);
            acc.w = fmaf(v.w, cf, acc.w);
        }
        *(float4*)&agg1[(size_t)n * HD + c4 * 4] = acc;
        float4 bv = ((const float4*)b1)[c4];
        float vx = acc.x + bv.x, vy = acc.y + bv.y, vz = acc.z + bv.z, vw = acc.w + bv.w;
        atomicAdd(&s0[c4 * 4 + 0], vx); atomicAdd(&s0[c4 * 4 + 1], vy);
        atomicAdd(&s0[c4 * 4 + 2], vz); atomicAdd(&s0[c4 * 4 + 3], vw);
        atomicAdd(&s1[c4 * 4 + 0], vx * vx); atomicAdd(&s1[c4 * 4 + 1], vy * vy);
        atomicAdd(&s1[c4 * 4 + 2], vz * vz); atomicAdd(&s1[c4 * 4 + 3], vw * vw);
    }
    __syncthreads();
    if (threadIdx.x < HD) {
        atomicAdd(&stats[threadIdx.x], s0[threadIdx.x]);
        atomicAdd(&stats[HD + threadIdx.x], s1[threadIdx.x]);
    }
}

// ---------------- gather2: colsc prologue + fused norm+relu+aggregate ----------------
__global__ __launch_bounds__(256) void k_gather2(const int* __restrict__ rowstart,
                                                 const int2* __restrict__ csr,
                                                 const float* __restrict__ agg1,
                                                 const float* __restrict__ stats,
                                                 const float* __restrict__ b1,
                                                 const float* __restrict__ gw,
                                                 const float* __restrict__ gb,
                                                 const float* __restrict__ ga,
                                                 float* __restrict__ aggh) {
    __shared__ float csc[2 * HD];
    if (threadIdx.x < HD) {
        int c = threadIdx.x;
        float m   = stats[c] * (1.0f / NN);
        float ex2 = stats[HD + c] * (1.0f / NN);
        float a   = ga[c];
        float var = ex2 - 2.0f * a * m * m + a * a * m * m;
        float sc  = gw[c] * rsqrtf(var + GEPS);
        csc[c]      = sc;
        csc[HD + c] = sc * (b1[c] - a * m) + gb[c];
    }
    __syncthreads();
    int t = blockIdx.x * 256 + threadIdx.x;
    if (t >= NN * 10) return;
    int n = t / 10, c4 = t % 10;
    int j0 = rowstart[n], j1 = rowstart[n + 1];
    float4 sc = ((const float4*)csc)[c4];
    float4 sh = ((const float4*)csc)[10 + c4];
    float4 acc = make_float4(0.f, 0.f, 0.f, 0.f);
#pragma unroll 2
    for (int j = j0; j < j1; ++j) {
        int2 se = csr[j];
        float cf = __int_as_float(se.y);
        float4 v = *(const float4*)&agg1[(size_t)se.x * HD + c4 * 4];
        v.x = fmaxf(fmaf(sc.x, v.x, sh.x), 0.f);
        v.y = fmaxf(fmaf(sc.y, v.y, sh.y), 0.f);
        v.z = fmaxf(fmaf(sc.z, v.z, sh.z), 0.f);
        v.w = fmaxf(fmaf(sc.w, v.w, sh.w), 0.f);
        acc.x = fmaf(v.x, cf, acc.x);
        acc.y = fmaf(v.y, cf, acc.y);
        acc.z = fmaf(v.z, cf, acc.z);
        acc.w = fmaf(v.w, cf, acc.w);
    }
    *(float4*)&aggh[(size_t)n * HD + c4 * 4] = acc;
}

// ---------------- heads (all three in one dispatch; z selects head) ----------------
__device__ __forceinline__ float activate_rt(float z, int act) {
    if (act == 0) {                    // mean: clip(exp, 1e-5, 1e6)
        return fminf(fmaxf(__expf(z), 1e-5f), 1e6f);
    } else if (act == 1) {             // disp: clip(softplus, 1e-4, 1e4)
        float sp = fmaxf(z, 0.0f) + __logf(1.0f + __expf(-fabsf(z)));
        return fminf(fmaxf(sp, 1e-4f), 1e4f);
    }
    return __fdividef(1.0f, 1.0f + __expf(-z));   // pi: sigmoid
}

#define FMA4(A, s, W)            \
    A.x = fmaf(s, W.x, A.x);     \
    A.y = fmaf(s, W.y, A.y);     \
    A.z = fmaf(s, W.z, A.z);     \
    A.w = fmaf(s, W.w, A.w);

// grid (ceil(NN/128), 4, 3). Block: 128 rows x 128 cols. Thread: 8 rows x 8 cols
// (col float4s cg and cg+16 -> 2-way-bank w_s reads; row blocks rg*2, rg*2+1).
__global__ __launch_bounds__(256) void k_heads3(const float* __restrict__ aggh,
                                                const float* __restrict__ Wm,
                                                const float* __restrict__ bm,
                                                const float* __restrict__ Wd,
                                                const float* __restrict__ bd,
                                                const float* __restrict__ Wp,
                                                const float* __restrict__ bp,
                                                float* __restrict__ out) {
    __shared__ float4 w_s[40 * 32];   // [k][32 float4-cols], 20 KB
    __shared__ float4 a_s[40 * 32];   // k-major, rotated 4-slot subtiles, 20 KB
    const int z = blockIdx.z;
    const float* W    = (z == 0) ? Wm : (z == 1) ? Wd : Wp;
    const float* bias = (z == 0) ? bm : (z == 1) ? bd : bp;
    float* o = out + (size_t)z * NN * FIN;

    const int t = threadIdx.x;
    const int rowbase = blockIdx.x * 128;
    const int colbase4 = blockIdx.y * 32;   // float4 units

    // stage W chunk [40][128] (straight copy, coalesced, conflict-free)
    const float4* W4 = (const float4*)W;
#pragma unroll
    for (int q = 0; q < 5; ++q) {
        int idx4 = t + 256 * q;
        int k = idx4 >> 5, cw = idx4 & 31;
        w_s[idx4] = W4[(size_t)k * 128 + colbase4 + cw];
    }
    // stage aggh tile transposed to k-major with 4-slot rotation
    const float4* A4 = (const float4*)aggh;
    float* as = (float*)a_s;
#pragma unroll
    for (int q = 0; q < 5; ++q) {
        int idx4 = t + 256 * q;                 // 1280 float4s = 128 rows x 10
        int row = idx4 / 10, c4 = idx4 % 10;
        int grow = min(rowbase + row, NN - 1);
        float4 v = A4[(size_t)grow * 10 + c4];
        int p = (row & ~15) + (((row & 15) + ((c4 & 3) << 2)) & 15);
        int k0 = c4 << 2;
        as[(k0 + 0) * 128 + p] = v.x;
        as[(k0 + 1) * 128 + p] = v.y;
        as[(k0 + 2) * 128 + p] = v.z;
        as[(k0 + 3) * 128 + p] = v.w;
    }
    __syncthreads();

    const int cg = t & 15;        // float4 column (and +16)
    const int rg = t >> 4;        // 8-row group (0..15)
    const int B0 = rg << 1, B1 = B0 | 1;

    float4 acc[16];
#pragma unroll
    for (int r = 0; r < 16; ++r) acc[r] = make_float4(0.f, 0.f, 0.f, 0.f);

#pragma unroll 2
    for (int kc = 0; kc < 10; ++kc) {
        const int rot = kc & 3;
        const int B0r = (B0 & ~3) | (((B0 & 3) + rot) & 3);
        const int B1r = (B1 & ~3) | (((B1 & 3) + rot) & 3);
#pragma unroll
        for (int kk = 0; kk < 4; ++kk) {
            const int k = (kc << 2) + kk;
            float4 wv0 = w_s[(k << 5) + cg];
            float4 wv1 = w_s[(k << 5) + 16 + cg];
            float4 av0 = a_s[(k << 5) + B0r];
            float4 av1 = a_s[(k << 5) + B1r];
            FMA4(acc[0],  av0.x, wv0)  FMA4(acc[1],  av0.x, wv1)
            FMA4(acc[2],  av0.y, wv0)  FMA4(acc[3],  av0.y, wv1)
            FMA4(acc[4],  av0.z, wv0)  FMA4(acc[5],  av0.z, wv1)
            FMA4(acc[6],  av0.w, wv0)  FMA4(acc[7],  av0.w, wv1)
            FMA4(acc[8],  av1.x, wv0)  FMA4(acc[9],  av1.x, wv1)
            FMA4(acc[10], av1.y, wv0)  FMA4(acc[11], av1.y, wv1)
            FMA4(acc[12], av1.z, wv0)  FMA4(acc[13], av1.z, wv1)
            FMA4(acc[14], av1.w, wv0)  FMA4(acc[15], av1.w, wv1)
        }
    }

    float4 bv0 = *(const float4*)&bias[(colbase4 + cg) * 4];
    float4 bv1 = *(const float4*)&bias[(colbase4 + 16 + cg) * 4];
    float4* out4 = (float4*)o;
#pragma unroll
    for (int rr = 0; rr < 8; ++rr) {
        int grow = rowbase + (rg << 3) + rr;
        if (grow < NN) {
            float4 a0 = acc[rr * 2], a1 = acc[rr * 2 + 1];
            float4 o0, o1;
            o0.x = activate_rt(a0.x + bv0.x, z);
            o0.y = activate_rt(a0.y + bv0.y, z);
            o0.z = activate_rt(a0.z + bv0.z, z);
            o0.w = activate_rt(a0.w + bv0.w, z);
            o1.x = activate_rt(a1.x + bv1.x, z);
            o1.y = activate_rt(a1.y + bv1.y, z);
            o1.z = activate_rt(a1.z + bv1.z, z);
            o1.w = activate_rt(a1.w + bv1.w, z);
            out4[(size_t)grow * 128 + colbase4 + cg] = o0;
            out4[(size_t)grow * 128 + colbase4 + 16 + cg] = o1;
        }
    }
}

extern "C" void kernel_launch(void* const* d_in, const int* in_sizes, int n_in,
                              void* d_out, int out_size, void* d_ws, size_t ws_size,
                              hipStream_t stream) {
    const float* x   = (const float*)d_in[0];
    const int*   src = (const int*)d_in[1];
    const int*   dst = (const int*)d_in[2];
    const float* W1  = (const float*)d_in[3];
    const float* b1  = (const float*)d_in[4];
    const float* gnw = (const float*)d_in[5];
    const float* gnb = (const float*)d_in[6];
    const float* gna = (const float*)d_in[7];
    const float* Wm  = (const float*)d_in[8];
    const float* bm  = (const float*)d_in[9];
    const float* Wd  = (const float*)d_in[10];
    const float* bd  = (const float*)d_in[11];
    const float* Wp  = (const float*)d_in[12];
    const float* bp  = (const float*)d_in[13];
    const int E = in_sizes[1];

    // workspace layout: zero-region (cnt,cur,stats) is 16B-aligned by construction
    float* ws       = (float*)d_ws;
    float* h1       = ws;                          // NN*HD  (mm1 out; later aggh)
    float* agg1     = h1 + (size_t)NN * HD;        // NN*HD  (gather1 out)
    int*   cnt      = (int*)(agg1 + (size_t)NN * HD);  // NN   } zeroed (int4)
    int*   cur      = cnt + NN;                    // NN     } zeroed
    float* stats    = (float*)(cur + NN);          // 2*HD   } zeroed
    float* dis      = stats + 2 * HD;              // NN
    int*   rowstart = (int*)(dis + NN);            // NN+1 (+1 pad for int2 align)
    int2*  csr      = (int2*)(rowstart + NN + 2);  // E int2, 8B-aligned
    float* out      = (float*)d_out;

    k_zero<<<(ZI4 + 255) / 256, 256, 0, stream>>>((int4*)cnt);
    k_hist<<<(E + 255) / 256, 256, 0, stream>>>(dst, cnt, E);
    k_scan<<<1, 256, 0, stream>>>(cnt, rowstart, dis);
    k_fill<<<(E + 255) / 256, 256, 0, stream>>>(src, dst, rowstart, cur, dis, csr, E);
    k_mm1<<<(NN + 63) / 64, 256, 0, stream>>>(x, W1, h1);
    k_gather1<<<(NN * 10 + 255) / 256, 256, 0, stream>>>(rowstart, csr, h1, b1, agg1, stats);
    k_gather2<<<(NN * 10 + 255) / 256, 256, 0, stream>>>(rowstart, csr, agg1, stats,
                                                         b1, gnw, gnb, gna, h1);
    dim3 hgrid((NN + 127) / 128, 4, 3);
    k_heads3<<<hgrid, 256, 0, stream>>>(h1, Wm, bm, Wd, bd, Wp, bp, out);
}